// Round 1
// baseline (47.936 us; speedup 1.0000x reference)
//
#include <hip/hip_runtime.h>
#include <hip/hip_bf16.h>

#define OUT_F 64
#define IN_F 64
#define M_PTS 20
#define BATCH 1024
#define NEDGE (OUT_F * IN_F)      // 4096
#define NCOEF (NEDGE * M_PTS)     // 81920

#if __has_builtin(__builtin_amdgcn_exp2f)
#define EXP2(x) __builtin_amdgcn_exp2f(x)
#else
#define EXP2(x) exp2f(x)
#endif

// Batch-independent per-(o,i,m) coefficients, recomputed every launch
// (deterministic; static device memory so no hipMalloc / d_ws dependency).
__device__ float4 g_coef[NCOEF];   // {z, qmc = c1*q_mu, A = c2*(q_mu^2+q_var), 0}
__device__ float2 g_na[NEDGE];     // {-log2e/(2*den1), -log2e/den2}

__global__ __launch_bounds__(256) void prep_kernel(
    const float* __restrict__ z, const float* __restrict__ q_mu,
    const float* __restrict__ q_log_var, const float* __restrict__ log_scale,
    const float* __restrict__ log_variance)
{
    int idx = blockIdx.x * 256 + threadIdx.x;
    if (idx >= NCOEF) return;
    int e = idx / M_PTS;          // e = o*IN_F + i
    int m = idx - e * M_PTS;

    float ell  = fmaxf(expf(log_scale[e]), 0.1f);
    float l2   = ell * ell;
    float sig2 = fmaxf(expf(log_variance[e]), 1e-5f);
    float den1 = l2 + 1e-6f;
    float den2 = l2 + 2e-6f;
    float c1 = sig2 * sqrtf(l2 / den1);
    float c2 = sig2 * sig2 * sqrtf(l2 / den2);

    float qm  = q_mu[idx];
    float qv  = fmaxf(expf(q_log_var[idx]), 1e-5f);
    float qmc = c1 * qm;
    float A   = c2 * (qm * qm + qv);

    g_coef[idx] = make_float4(z[idx], qmc, A, 0.0f);
    if (m == 0) {
        const float LOG2E = 1.4426950408889634f;
        g_na[e] = make_float2(-LOG2E / (2.0f * den1), -LOG2E / den2);
    }
}

// Grid: (BATCH/64, OUT_F). Block: 256 threads = 4 waves.
// Wave w handles i in [w*16, w*16+16); lane = local batch index.
__global__ __launch_bounds__(256) void gpkan_main(
    const float* __restrict__ x, float* __restrict__ out)
{
    const int o    = blockIdx.y;
    const int lane = threadIdx.x & 63;
    const int wv   = __builtin_amdgcn_readfirstlane(threadIdx.x >> 6); // 0..3 (SGPR)
    const int b    = blockIdx.x * 64 + lane;

    const float4* __restrict__ xp =
        reinterpret_cast<const float4*>(x + (b * IN_F + wv * 16));

    float mean = 0.0f, var = 0.0f;

    for (int gg = 0; gg < 4; ++gg) {
        float4 xq = xp[gg];
        float xe[4] = {xq.x, xq.y, xq.z, xq.w};
        #pragma unroll
        for (int ee = 0; ee < 4; ++ee) {
            const int i = wv * 16 + gg * 4 + ee;
            const int e = o * IN_F + i;
            const float2 na = g_na[e];
            const float4* __restrict__ cp = g_coef + e * M_PTS;
            const float xb = xe[ee];
            float em = 0.0f, ev = 0.0f;
            #pragma unroll
            for (int m = 0; m < M_PTS; ++m) {
                float4 c  = cp[m];
                float t   = xb - c.x;
                float d2  = t * t;
                float e1  = EXP2(d2 * na.x);
                float e2  = EXP2(d2 * na.y);
                float s   = e1 * c.y;
                em += s;
                ev  = fmaf(e2, c.z, ev);
                ev  = fmaf(-s, s, ev);
            }
            mean += em;
            var  += fmaxf(ev, 0.0f);   // per-edge clip BEFORE i-sum (matches ref)
        }
    }

    __shared__ float red_m[256];
    __shared__ float red_v[256];
    red_m[threadIdx.x] = mean;
    red_v[threadIdx.x] = var;
    __syncthreads();
    if (threadIdx.x < 64) {
        float ms = red_m[threadIdx.x] + red_m[threadIdx.x + 64] +
                   red_m[threadIdx.x + 128] + red_m[threadIdx.x + 192];
        float vs = red_v[threadIdx.x] + red_v[threadIdx.x + 64] +
                   red_v[threadIdx.x + 128] + red_v[threadIdx.x + 192];
        int bb = blockIdx.x * 64 + threadIdx.x;
        out[bb * OUT_F + o] = ms;
        out[BATCH * OUT_F + bb * OUT_F + o] = vs;
    }
}

extern "C" void kernel_launch(void* const* d_in, const int* in_sizes, int n_in,
                              void* d_out, int out_size, void* d_ws, size_t ws_size,
                              hipStream_t stream) {
    const float* x            = (const float*)d_in[0];
    const float* z            = (const float*)d_in[1];
    const float* q_mu         = (const float*)d_in[2];
    const float* q_log_var    = (const float*)d_in[3];
    const float* log_scale    = (const float*)d_in[4];
    const float* log_variance = (const float*)d_in[5];
    float* out = (float*)d_out;

    prep_kernel<<<(NCOEF + 255) / 256, 256, 0, stream>>>(
        z, q_mu, q_log_var, log_scale, log_variance);
    gpkan_main<<<dim3(BATCH / 64, OUT_F), 256, 0, stream>>>(x, out);
}

// Round 2
// 30.824 us; speedup vs baseline: 1.5552x; 1.5552x over previous
//
#include <hip/hip_runtime.h>
#include <hip/hip_bf16.h>

#define OUT_F 64
#define IN_F 64
#define M_PTS 20
#define BATCH 1024

#if __has_builtin(__builtin_amdgcn_exp2f)
#define EXP2(x) __builtin_amdgcn_exp2f(x)
#else
#define EXP2(x) exp2f(x)
#endif

// Single fused kernel. Grid (BATCH/64, OUT_F), 256 threads = 4 waves.
// Phase 1: block recomputes its o's 64*20 coefficient float4s into LDS.
//   c = {z, qmc = c1*q_mu, B = A - qmc^2, Ak = A*k}
//   where A = c2*(qm^2+qv), k = 1e-6/(den1*den2).
//   Inner identity: edge_var contrib = e1^2 * (B + Ak*d2)  [exp(d2*k)
//   linearized to 1+d2*k; exact to ~1e-9 for benchmark params].
// Phase 2: wave wv handles i in [wv*16, wv*16+16), lane = local batch.
__global__ __launch_bounds__(256) void gpkan_fused(
    const float* __restrict__ x, const float* __restrict__ z,
    const float* __restrict__ q_mu, const float* __restrict__ q_log_var,
    const float* __restrict__ log_scale, const float* __restrict__ log_variance,
    float* __restrict__ out)
{
    __shared__ float4 c_lds[IN_F * M_PTS];   // 20480 B
    __shared__ float na1_lds[IN_F];          // 256 B
    __shared__ float red_m[256];
    __shared__ float red_v[256];

    const int o   = blockIdx.y;
    const int tid = threadIdx.x;

    // ---- phase 1: coefficients (5 entries per thread) ----
    const float LOG2E = 1.4426950408889634f;
    #pragma unroll
    for (int k = 0; k < 5; ++k) {
        const int idx = tid + k * 256;       // idx = i*M_PTS + m
        const int i   = idx / M_PTS;
        const int m   = idx - i * M_PTS;
        const int e   = o * IN_F + i;
        const int ge  = e * M_PTS + m;

        float ell  = fmaxf(expf(log_scale[e]), 0.1f);
        float l2   = ell * ell;
        float sig2 = fmaxf(expf(log_variance[e]), 1e-5f);
        float den1 = l2 + 1e-6f;
        float den2 = l2 + 2e-6f;
        float c1   = sig2 * sqrtf(l2 / den1);
        float c2   = sig2 * sig2 * sqrtf(l2 / den2);
        float kk   = 1e-6f / (den1 * den2);

        float qm  = q_mu[ge];
        float qv  = fmaxf(expf(q_log_var[ge]), 1e-5f);
        float qmc = c1 * qm;
        float A   = c2 * (qm * qm + qv);

        c_lds[idx] = make_float4(z[ge], qmc, A - qmc * qmc, A * kk);
        if (m == 0) na1_lds[i] = -0.5f * LOG2E / den1;
    }
    __syncthreads();

    // ---- phase 2: hot loop ----
    const int lane = tid & 63;
    const int wv   = __builtin_amdgcn_readfirstlane(tid >> 6);
    const int b    = blockIdx.x * 64 + lane;
    const float4* __restrict__ xp =
        reinterpret_cast<const float4*>(x + (b * IN_F + wv * 16));

    float mean = 0.0f, var = 0.0f;

    for (int gg = 0; gg < 4; ++gg) {
        float4 xq = xp[gg];
        float xe[4] = {xq.x, xq.y, xq.z, xq.w};
        #pragma unroll
        for (int ee = 0; ee < 4; ++ee) {
            const int i = wv * 16 + gg * 4 + ee;
            const float na1 = na1_lds[i];
            const float4* __restrict__ cp = c_lds + i * M_PTS;
            const float xb = xe[ee];
            float em = 0.0f, ev = 0.0f;
            #pragma unroll
            for (int m = 0; m < M_PTS; ++m) {
                float4 c  = cp[m];            // wave-uniform ds_read_b128 (broadcast)
                float t   = xb - c.x;
                float d2  = t * t;
                float e1  = EXP2(d2 * na1);   // exp(-d2/(2*den1))
                float u   = e1 * e1;          // exp(-d2/den1)
                float w   = fmaf(c.w, d2, c.z);  // B + Ak*d2
                ev = fmaf(u, w, ev);
                em = fmaf(e1, c.y, em);
            }
            mean += em;
            var  += fmaxf(ev, 0.0f);          // per-edge clip before i-sum
        }
    }

    red_m[tid] = mean;
    red_v[tid] = var;
    __syncthreads();
    if (tid < 64) {
        float ms = red_m[tid] + red_m[tid + 64] + red_m[tid + 128] + red_m[tid + 192];
        float vs = red_v[tid] + red_v[tid + 64] + red_v[tid + 128] + red_v[tid + 192];
        int bb = blockIdx.x * 64 + tid;
        out[bb * OUT_F + o] = ms;
        out[BATCH * OUT_F + bb * OUT_F + o] = vs;
    }
}

extern "C" void kernel_launch(void* const* d_in, const int* in_sizes, int n_in,
                              void* d_out, int out_size, void* d_ws, size_t ws_size,
                              hipStream_t stream) {
    const float* x            = (const float*)d_in[0];
    const float* z            = (const float*)d_in[1];
    const float* q_mu         = (const float*)d_in[2];
    const float* q_log_var    = (const float*)d_in[3];
    const float* log_scale    = (const float*)d_in[4];
    const float* log_variance = (const float*)d_in[5];
    float* out = (float*)d_out;

    gpkan_fused<<<dim3(BATCH / 64, OUT_F), 256, 0, stream>>>(
        x, z, q_mu, q_log_var, log_scale, log_variance, out);
}

// Round 3
// 30.251 us; speedup vs baseline: 1.5846x; 1.0189x over previous
//
#include <hip/hip_runtime.h>
#include <hip/hip_bf16.h>

#define OUT_F 64
#define IN_F 64
#define M_PTS 20
#define BATCH 1024
#define BCHUNK 16                      // batch elems per wave
#define NB (BATCH / BCHUNK)            // 64 batch chunks

#if __has_builtin(__builtin_amdgcn_exp2f)
#define EXP2(x) __builtin_amdgcn_exp2f(x)
#else
#define EXP2(x) exp2f(x)
#endif

// Transposed coefficient tables (batch-independent, rebuilt every launch).
// g_c4[o][m][i] = {Zs = s*z, qmc = c1*q_mu, B = A - qmc^2, Akp}
//   s   = sqrt(log2e / (2*den1))            (so arg = -(s*(x-z))^2 = -d2*log2e/(2den1))
//   A   = c2*(qm^2+qv),  kk = 1e-6/(den1*den2)
//   Akp = -2*A*kk*den1/log2e               (so A*kk*d2 == Akp*arg)
// var contrib = e1^2 * (B + Akp*arg)   [exp(kk*d2) linearized; err ~1e-9]
__device__ float4 g_c4[OUT_F * M_PTS * IN_F];
__device__ float  g_s [OUT_F * IN_F];

__global__ __launch_bounds__(256) void prep_kernel(
    const float* __restrict__ z, const float* __restrict__ q_mu,
    const float* __restrict__ q_log_var, const float* __restrict__ log_scale,
    const float* __restrict__ log_variance)
{
    int idx = blockIdx.x * 256 + threadIdx.x;      // idx = (o*20+m)*64 + i
    if (idx >= OUT_F * M_PTS * IN_F) return;
    int i  = idx & 63;
    int om = idx >> 6;
    int m  = om % M_PTS;
    int o  = om / M_PTS;
    int e  = o * IN_F + i;
    int ge = e * M_PTS + m;

    const float LOG2E = 1.4426950408889634f;
    float ell  = fmaxf(expf(log_scale[e]), 0.1f);
    float l2   = ell * ell;
    float sig2 = fmaxf(expf(log_variance[e]), 1e-5f);
    float den1 = l2 + 1e-6f;
    float den2 = l2 + 2e-6f;
    float c1   = sig2 * sqrtf(l2 / den1);
    float c2   = sig2 * sig2 * sqrtf(l2 / den2);
    float kk   = 1e-6f / (den1 * den2);
    float s    = sqrtf(0.5f * LOG2E / den1);

    float qm  = q_mu[ge];
    float qv  = fmaxf(expf(q_log_var[ge]), 1e-5f);
    float qmc = c1 * qm;
    float A   = c2 * (qm * qm + qv);
    float B   = A - qmc * qmc;
    float Akp = -2.0f * A * kk * den1 / LOG2E;

    g_c4[idx] = make_float4(s * z[ge], qmc, B, Akp);
    if (m == 0) g_s[(o << 6) + i] = s;
}

// Grid: NB*OUT_F single-wave blocks. lane = i. Hot loop is memory-free:
// all coefficients in VGPRs, 16 batch elems per lane.
__global__ __launch_bounds__(64, 2) void gpkan_main(
    const float* __restrict__ x, float* __restrict__ out)
{
    const int blk  = blockIdx.x;
    const int o    = blk & 63;
    const int bc   = blk >> 6;           // batch chunk
    const int lane = threadIdx.x;        // = i

    const float s = g_s[(o << 6) + lane];

    float4 c[M_PTS];
    #pragma unroll
    for (int m = 0; m < M_PTS; ++m)
        c[m] = g_c4[(o * M_PTS + m) * IN_F + lane];   // coalesced dwordx4

    float xs[BCHUNK];
    #pragma unroll
    for (int bb = 0; bb < BCHUNK; ++bb)
        xs[bb] = s * x[(bc * BCHUNK + bb) * IN_F + lane];  // coalesced

    float em[BCHUNK], ev[BCHUNK];
    #pragma unroll
    for (int bb = 0; bb < BCHUNK; ++bb) {
        float e_m = 0.0f, e_v = 0.0f;
        #pragma unroll
        for (int m = 0; m < M_PTS; ++m) {
            float t   = xs[bb] - c[m].x;
            float nt  = -t;
            float arg = nt * t;               // -(s(x-z))^2, neg folds to modifier
            float e1  = EXP2(arg);
            float u   = e1 * e1;
            float w   = fmaf(c[m].w, arg, c[m].z);
            e_v = fmaf(u, w, e_v);
            e_m = fmaf(e1, c[m].y, e_m);
        }
        em[bb] = e_m;
        ev[bb] = fmaxf(e_v, 0.0f);            // per-edge clip (lane = full edge)
    }

    // Cross-lane (i) reduction: LDS transpose + 2-level shfl.
    __shared__ float2 red[BCHUNK][65];
    #pragma unroll
    for (int bb = 0; bb < BCHUNK; ++bb)
        red[bb][lane] = make_float2(em[bb], ev[bb]);
    __syncthreads();

    const int bb = lane & 15;
    const int g  = lane >> 4;
    float sm = 0.0f, sv = 0.0f;
    #pragma unroll
    for (int j = 0; j < 16; ++j) {
        float2 v = red[bb][g * 16 + j];
        sm += v.x;
        sv += v.y;
    }
    sm += __shfl_xor(sm, 16); sv += __shfl_xor(sv, 16);
    sm += __shfl_xor(sm, 32); sv += __shfl_xor(sv, 32);

    if (lane < 16) {
        int b = bc * BCHUNK + lane;
        out[b * OUT_F + o] = sm;
        out[BATCH * OUT_F + b * OUT_F + o] = sv;
    }
}

extern "C" void kernel_launch(void* const* d_in, const int* in_sizes, int n_in,
                              void* d_out, int out_size, void* d_ws, size_t ws_size,
                              hipStream_t stream) {
    const float* x            = (const float*)d_in[0];
    const float* z            = (const float*)d_in[1];
    const float* q_mu         = (const float*)d_in[2];
    const float* q_log_var    = (const float*)d_in[3];
    const float* log_scale    = (const float*)d_in[4];
    const float* log_variance = (const float*)d_in[5];
    float* out = (float*)d_out;

    prep_kernel<<<(OUT_F * M_PTS * IN_F + 255) / 256, 256, 0, stream>>>(
        z, q_mu, q_log_var, log_scale, log_variance);
    gpkan_main<<<NB * OUT_F, 64, 0, stream>>>(x, out);
}